// Round 6
// baseline (180.930 us; speedup 1.0000x reference)
//
#include <hip/hip_runtime.h>
#include <stdint.h>

// ---------------------------------------------------------------------------
// MultiHeadSelfAttention: x(2,2048,1024) fp32, w_qkv(1024,3072), w_out(1024,1024)
// R5: attn is issue-bound (R4 PMC: VALU 50k + LDS 58k + MFMA 16k ≈ 124k of
// 132k cyc/CU). Waves now own 32 q-rows (2 qf frags): K/V ds_read_b128,
// staging, and loop overhead HALVE per q-row (frags shared across qf);
// P-pack uses (__bf16) casts -> v_cvt_pk_bf16_f32. In-register P via k-slot
// permutation kept from R4. GEMMs unchanged.
// ---------------------------------------------------------------------------

#define B_ 2
#define T_ 2048
#define C_ 1024
#define H_ 16
#define D_ 64
#define F_ 3072
#define M_ 4096

typedef unsigned short u16;
typedef unsigned int u32;
typedef u16 u16x2 __attribute__((ext_vector_type(2)));
typedef u16 u16x4 __attribute__((ext_vector_type(4)));
typedef u16 u16x8 __attribute__((ext_vector_type(8)));
typedef __bf16 bf16x8 __attribute__((ext_vector_type(8)));
typedef float f32x4 __attribute__((ext_vector_type(4)));

__device__ __forceinline__ float b2f(u16 u) {
  union { unsigned int i; float f; } v; v.i = ((unsigned int)u) << 16; return v.f;
}
__device__ __forceinline__ u16 f2b(float f) {  // RNE, finite inputs
  unsigned int u = __float_as_uint(f);
  u += 0x7fffu + ((u >> 16) & 1u);
  return (u16)(u >> 16);
}
__device__ __forceinline__ bf16x8 u2b8(u16x8 v) {
  union { u16x8 u; bf16x8 b; } x; x.u = v; return x.b;
}

// --------------------------- small prep kernels ----------------------------

__global__ __launch_bounds__(256) void rope_table_kernel(float* cosT, float* sinT) {
  int idx = blockIdx.x * 256 + threadIdx.x;    // T_*32 = 65536 threads
  int t = idx >> 5, i = idx & 31;
  float inv_freq = powf(10000.0f, -(float)(2 * i) / 64.0f);
  float ang = (float)t * inv_freq;
  cosT[idx] = cosf(ang);
  sinT[idx] = sinf(ang);
}

__global__ __launch_bounds__(256) void cast_x_kernel(const float* __restrict__ x,
                                                     u16* __restrict__ xb) {
  int i = blockIdx.x * 256 + threadIdx.x;      // M_*C_/4 threads
  float4 v = ((const float4*)x)[i];
  u16x4 r;
  r[0] = f2b(v.x); r[1] = f2b(v.y); r[2] = f2b(v.z); r[3] = f2b(v.w);
  ((u16x4*)xb)[i] = r;
}

// out[c][r] = bf16(in[r][c]);  R rows, Ccol cols in input. 32x32 tiles.
__global__ __launch_bounds__(256) void transpose_cast_kernel(const float* __restrict__ in,
                                                             u16* __restrict__ out,
                                                             int R, int Ccol) {
  __shared__ float tile[32][33];
  int c0 = blockIdx.x * 32, r0 = blockIdx.y * 32;
  int tx = threadIdx.x & 31, ty = threadIdx.x >> 5;   // ty = 0..7
  #pragma unroll
  for (int i = 0; i < 32; i += 8)
    tile[ty + i][tx] = in[(size_t)(r0 + ty + i) * Ccol + c0 + tx];
  __syncthreads();
  #pragma unroll
  for (int i = 0; i < 32; i += 8)
    out[(size_t)(c0 + ty + i) * R + r0 + tx] = f2b(tile[tx][ty + i]);
}

// ------------------------------- MFMA GEMM ---------------------------------
// C[M,N] = A[M,K] * Bt[N,K]^T, bf16 in, TO out. 128x128 tile, BK=32, 4 waves,
// 4x4 16x16x32 frags. Staging via global_load_lds width=16 (m97 structure).
template <typename TO>
__global__ __launch_bounds__(256) void gemm_bt_kernel(const u16* __restrict__ A,
                                                      const u16* __restrict__ Bt,
                                                      TO* __restrict__ Cm,
                                                      int M, int N, int K) {
  __shared__ u16 sA[128 * 32];
  __shared__ u16 sB[128 * 32];
  const int tid = threadIdx.x;
  const int lane = tid & 63;
  const int wv = tid >> 6;
  const int wr = wv >> 1, wc = wv & 1;
  const int l16 = lane & 15, lq = lane >> 4;
  const int rowBase = blockIdx.y * 128;
  const int colBase = blockIdx.x * 128;

  f32x4 acc[4][4] = {};

  const int e0 = wv * 1024 + lane * 8;      // this lane's elem offset, chunk 0

  for (int k0 = 0; k0 < K; k0 += 32) {
    #pragma unroll
    for (int s = 0; s < 2; ++s) {
      int e = e0 + s * 512;
      int r = e >> 5, c = e & 31;
      __builtin_amdgcn_global_load_lds(
          (const __attribute__((address_space(1))) u32*)(A + (size_t)(rowBase + r) * K + k0 + c),
          (__attribute__((address_space(3))) u32*)&sA[wv * 1024 + s * 512], 16, 0, 0);
      __builtin_amdgcn_global_load_lds(
          (const __attribute__((address_space(1))) u32*)(Bt + (size_t)(colBase + r) * K + k0 + c),
          (__attribute__((address_space(3))) u32*)&sB[wv * 1024 + s * 512], 16, 0, 0);
    }
    __syncthreads();   // drains vmcnt (incl. global_load_lds) per compiler rule
    bf16x8 af[4], bf[4];
    #pragma unroll
    for (int m = 0; m < 4; ++m)
      af[m] = u2b8(*(const u16x8*)&sA[(wr * 64 + m * 16 + l16) * 32 + lq * 8]);
    #pragma unroll
    for (int n = 0; n < 4; ++n)
      bf[n] = u2b8(*(const u16x8*)&sB[(wc * 64 + n * 16 + l16) * 32 + lq * 8]);
    #pragma unroll
    for (int m = 0; m < 4; ++m)
      #pragma unroll
      for (int n = 0; n < 4; ++n)
        acc[m][n] = __builtin_amdgcn_mfma_f32_16x16x32_bf16(af[m], bf[n], acc[m][n], 0, 0, 0);
    __syncthreads();
  }

  // C/D layout (verified m89): col = lane&15, row = (lane>>4)*4 + reg
  #pragma unroll
  for (int m = 0; m < 4; ++m) {
    #pragma unroll
    for (int n = 0; n < 4; ++n) {
      int row = rowBase + wr * 64 + m * 16 + lq * 4;
      int col = colBase + wc * 64 + n * 16 + l16;
      #pragma unroll
      for (int j = 0; j < 4; ++j) {
        float v = acc[m][n][j];
        if constexpr (sizeof(TO) == 2) {
          Cm[(size_t)(row + j) * N + col] = f2b(v);
        } else {
          Cm[(size_t)(row + j) * N + col] = v;
        }
      }
    }
  }
}

// ----------------------------- RoPE + reorg --------------------------------
// qkv[M_,F_] bf16 -> qr/kr/vr [B,H,T,D] bf16 (rope on q,k; copy v)
// qr is PRE-SCALED by 0.125*log2(e) (exp2-domain softmax, single bf16 round).
__global__ __launch_bounds__(256) void rope_reorg_kernel(const u16* __restrict__ qkv,
                                                         const float* __restrict__ cosT,
                                                         const float* __restrict__ sinT,
                                                         u16* __restrict__ qr,
                                                         u16* __restrict__ kr,
                                                         u16* __restrict__ vr) {
  const float QSC = 0.125f * 1.44269504f;
  int idx = blockIdx.x * 256 + threadIdx.x;   // B*T*H*32 = 2^21 threads
  int d2 = idx & 31;
  int h = (idx >> 5) & 15;
  int t = (idx >> 9) & 2047;
  int b = idx >> 20;
  size_t base = (size_t)(b * T_ + t) * F_ + h * 64 + d2 * 2;
  float qe = b2f(qkv[base]),        qo = b2f(qkv[base + 1]);
  float ke = b2f(qkv[base + C_]),   ko = b2f(qkv[base + C_ + 1]);
  float cv = cosT[t * 32 + d2], sv = sinT[t * 32 + d2];
  size_t ob = ((size_t)(b * H_ + h) * T_ + t) * D_ + d2 * 2;
  qr[ob]     = f2b((qe * cv - qo * sv) * QSC);
  qr[ob + 1] = f2b((qe * sv + qo * cv) * QSC);
  kr[ob]     = f2b(ke * cv - ko * sv);
  kr[ob + 1] = f2b(ke * sv + ko * cv);
  vr[ob]     = qkv[base + 2 * C_];
  vr[ob + 1] = qkv[base + 2 * C_ + 1];
}

// ------------------------- MFMA flash attention ----------------------------
// Swapped QK^T; softmax state in q=l16 space, O accumulator in q=lq*4+j space;
// cross-space transfers via __shfl(.., lq*4+j) (R2-verified).
// R4: in-register P via k-slot permutation (V rows staged bit-permuted
// vrow = [b5 b2 b4 b3 b1 b0] so PV A-operand = own exp2'd registers).
// R5: 32 q-rows/wave (2 qf frags, R3-verified bookkeeping): K-frags and
// V-frags read ONCE per tile, shared by both qf -> LDS reads/staging/loop
// overhead halve per q-row. P-pack via (__bf16) casts (v_cvt_pk_bf16_f32).
__global__ __launch_bounds__(256, 4) void attn_mfma_kernel(const u16* __restrict__ qr,
                                                           const u16* __restrict__ kr,
                                                           const u16* __restrict__ vr,
                                                           u16* __restrict__ ao) {
  constexpr int LDK = 72, LDVT = 72;
  __shared__ u16 sK[2][64 * LDK];
  __shared__ u16 sVt[2][64 * LDVT];              // sVt[buf][d][k-slot]

  const int tid = threadIdx.x;
  const int lane = tid & 63;
  const int w = tid >> 6;
  const int l16 = lane & 15, lq = lane >> 4;
  const int bh = blockIdx.x;
  const int qt = (int)gridDim.y - 1 - (int)blockIdx.y;   // long blocks first
  const int qbase = qt * 128;                            // 128 q-rows/block
  const size_t hb = (size_t)bh * (T_ * D_);

  // Q frags (pre-scaled bf16): rows qbase + w*32 + qf*16 + l16
  bf16x8 qv[2][2];
  #pragma unroll
  for (int qf = 0; qf < 2; ++qf)
    #pragma unroll
    for (int dc = 0; dc < 2; ++dc) {
      int row = qbase + w * 32 + qf * 16 + l16;
      qv[qf][dc] = u2b8(*(const u16x8*)(qr + hb + (size_t)row * 64 + dc * 32 + lq * 8));
    }

  f32x4 o[2][4] = {};                 // o[qf][dt]: O[q=lq*4+j][d=dt*16+l16]
  float mrow[2] = {-1e30f, -1e30f};   // running max (log2 domain), row q=l16
  float lrow[2] = {0.0f, 0.0f};       // per-lane partial denom, row q=l16

  // staging index maps
  const int skk = tid >> 3;           // K row 0..31 (and +32)
  const int sd0 = (tid & 7) * 8;      // K col octet
  const int vkp = tid & 31;           // V slot-pair 0..31 (slots 2vkp, 2vkp+1)
  const int vdb = tid >> 5;           // V d-block 0..7
  // true V row for slot r=2*vkp: vrow(r)=32*b5+16*b2+8*b4+4*b3+2*b1+b0 (r bits)
  const int vtr = ((vkp >> 4) & 1) * 32 + ((vkp >> 1) & 1) * 16 +
                  ((vkp >> 3) & 1) * 8 + ((vkp >> 2) & 1) * 4 + (vkp & 1) * 2;

  u16x8 rk0, rk1, rv0, rv1;
#define LOADKV(k0)                                                             \
  {                                                                            \
    rk0 = *(const u16x8*)(kr + hb + (size_t)((k0) + skk) * 64 + sd0);          \
    rk1 = *(const u16x8*)(kr + hb + (size_t)((k0) + 32 + skk) * 64 + sd0);     \
    rv0 = *(const u16x8*)(vr + hb + (size_t)((k0) + vtr) * 64 + vdb * 8);      \
    rv1 = *(const u16x8*)(vr + hb + (size_t)((k0) + vtr + 1) * 64 + vdb * 8);  \
  }
#define WRITEKV(buf)                                                           \
  {                                                                            \
    *(u16x8*)&sK[buf][skk * LDK + sd0] = rk0;                                  \
    *(u16x8*)&sK[buf][(32 + skk) * LDK + sd0] = rk1;                           \
    _Pragma("unroll")                                                          \
    for (int u = 0; u < 8; ++u) {                                              \
      u16x2 pk; pk[0] = rv0[u]; pk[1] = rv1[u];                                \
      *(u16x2*)&sVt[buf][(vdb * 8 + u) * LDVT + 2 * vkp] = pk;                 \
    }                                                                          \
  }

  LOADKV(0);
  WRITEKV(0);
  __syncthreads();

  const int qmaxw = qbase + w * 32 + 31;   // max q-row this wave owns
  const int nt = qt * 2 + 2;
  int cur = 0;
  for (int it = 0; it < nt; ++it) {
    const int k0 = it * 64;
    const bool more = (it + 1 < nt);
    if (more) LOADKV(k0 + 64);           // prefetch next tile into regs (T14)

    if (k0 <= qmaxw) {                   // else fully masked for this wave
      // ---- QK^T (swapped): accs[qf][kt][j] = S[q=l16][slot k0+kt*16+lq*4+j]
      f32x4 accs[2][4] = {};
      __builtin_amdgcn_s_setprio(1);
      #pragma unroll
      for (int kt = 0; kt < 4; ++kt) {
        bf16x8 kf0 = u2b8(*(const u16x8*)&sK[cur][(kt * 16 + l16) * LDK + lq * 8]);
        bf16x8 kf1 = u2b8(*(const u16x8*)&sK[cur][(kt * 16 + l16) * LDK + 32 + lq * 8]);
        accs[0][kt] = __builtin_amdgcn_mfma_f32_16x16x32_bf16(kf0, qv[0][0], accs[0][kt], 0, 0, 0);
        accs[0][kt] = __builtin_amdgcn_mfma_f32_16x16x32_bf16(kf1, qv[0][1], accs[0][kt], 0, 0, 0);
        accs[1][kt] = __builtin_amdgcn_mfma_f32_16x16x32_bf16(kf0, qv[1][0], accs[1][kt], 0, 0, 0);
        accs[1][kt] = __builtin_amdgcn_mfma_f32_16x16x32_bf16(kf1, qv[1][1], accs[1][kt], 0, 0, 0);
      }
      __builtin_amdgcn_s_setprio(0);

      bf16x8 pb[2][2];                   // pb[qf][kc]: PV A-operand (own regs)
      #pragma unroll
      for (int qf = 0; qf < 2; ++qf) {
        const int qrow = qbase + w * 32 + qf * 16 + l16;
        if (k0 + 63 > qbase + w * 32 + qf * 16) {   // wave-uniform per qf
          #pragma unroll
          for (int kt = 0; kt < 4; ++kt)
            #pragma unroll
            for (int j = 0; j < 4; ++j)
              if (k0 + kt * 16 + lq * 4 + j > qrow) accs[qf][kt][j] = -1e30f;
        }
        // row max for q=l16: depth-4 tree + 2 shfl (k spread across lq groups)
        float m0 = fmaxf(fmaxf(accs[qf][0][0], accs[qf][0][1]), fmaxf(accs[qf][0][2], accs[qf][0][3]));
        float m1 = fmaxf(fmaxf(accs[qf][1][0], accs[qf][1][1]), fmaxf(accs[qf][1][2], accs[qf][1][3]));
        float m2 = fmaxf(fmaxf(accs[qf][2][0], accs[qf][2][1]), fmaxf(accs[qf][2][2], accs[qf][2][3]));
        float m3 = fmaxf(fmaxf(accs[qf][3][0], accs[qf][3][1]), fmaxf(accs[qf][3][2], accs[qf][3][3]));
        float mx = fmaxf(fmaxf(m0, m1), fmaxf(m2, m3));
        mx = fmaxf(mx, __shfl_xor(mx, 16));
        mx = fmaxf(mx, __shfl_xor(mx, 32));

        if (!__all(mx <= mrow[qf])) {    // defer-max: exact skip when no new max
          float mnew = fmaxf(mrow[qf], mx);
          float corr = __builtin_amdgcn_exp2f(mrow[qf] - mnew);   // row q=l16
          lrow[qf] *= corr;
          mrow[qf] = mnew;
          // broadcast corr into D-row space (q=lq*4+j) before scaling O
          f32x4 corrv;
          #pragma unroll
          for (int j = 0; j < 4; ++j) corrv[j] = __shfl(corr, lq * 4 + j);
          #pragma unroll
          for (int dt = 0; dt < 4; ++dt) o[qf][dt] *= corrv;
        }
        const float mu = mrow[qf];
        float lsum = 0.0f;
        #pragma unroll
        for (int kt = 0; kt < 4; ++kt) {
          #pragma unroll
          for (int j = 0; j < 4; ++j) {
            float p = __builtin_amdgcn_exp2f(accs[qf][kt][j] - mu);
            lsum += p;
            pb[qf][kt >> 1][(kt & 1) * 4 + j] = (__bf16)p;   // -> v_cvt_pk_bf16_f32
          }
        }
        lrow[qf] += lsum;
      }

      // ---- PV: A = own registers (slot perm); B from sVt, shared across qf
      __builtin_amdgcn_s_setprio(1);
      #pragma unroll
      for (int kc = 0; kc < 2; ++kc) {
        #pragma unroll
        for (int dt = 0; dt < 4; ++dt) {
          bf16x8 vt = u2b8(*(const u16x8*)&sVt[cur][(dt * 16 + l16) * LDVT + kc * 32 + lq * 8]);
          o[0][dt] = __builtin_amdgcn_mfma_f32_16x16x32_bf16(pb[0][kc], vt, o[0][dt], 0, 0, 0);
          o[1][dt] = __builtin_amdgcn_mfma_f32_16x16x32_bf16(pb[1][kc], vt, o[1][dt], 0, 0, 0);
        }
      }
      __builtin_amdgcn_s_setprio(0);
    }

    if (more) WRITEKV(cur ^ 1);          // write prefetched tile to other buffer
    __syncthreads();                     // one barrier per tile
    cur ^= 1;
  }

  // finalize: full row denom in l16-space, broadcast 1/l into D-row space.
  const int b = bh >> 4, h = bh & 15;
  #pragma unroll
  for (int qf = 0; qf < 2; ++qf) {
    float l = lrow[qf];
    l += __shfl_xor(l, 16);
    l += __shfl_xor(l, 32);
    float linv = 1.0f / l;
    #pragma unroll
    for (int j = 0; j < 4; ++j) {
      float lj = __shfl(linv, lq * 4 + j);   // lane r (r<16) holds row r's denom
      int row = qbase + w * 32 + qf * 16 + lq * 4 + j;
      u16* orow = ao + ((size_t)(b * T_ + row)) * C_ + h * 64;
      #pragma unroll
      for (int dt = 0; dt < 4; ++dt)
        orow[dt * 16 + l16] = f2b(o[qf][dt][j] * lj);
    }
  }
}

// ------------------------------- launcher ----------------------------------
// ws layout (bytes):                              size
//   xb     @ 0           bf16 x           8,388,608
//   wqkvT  @ 8388608     bf16 w_qkv^T     6,291,456
//   woutT  @ 14680064    bf16 w_out^T     2,097,152
//   qkv    @ 16777216    bf16 qkv        25,165,824
//   qr     @ 41943040    bf16 [B,H,T,D]   8,388,608
//   kr     @ 50331648                     8,388,608
//   vr     @ 58720256                     8,388,608
//   ao     @ 67108864    bf16 attn out    8,388,608
//   cosT   @ 75497472    f32                262,144
//   sinT   @ 75759616    f32                262,144
extern "C" void kernel_launch(void* const* d_in, const int* in_sizes, int n_in,
                              void* d_out, int out_size, void* d_ws, size_t ws_size,
                              hipStream_t stream) {
  const float* x     = (const float*)d_in[0];
  const float* w_qkv = (const float*)d_in[1];
  const float* w_out = (const float*)d_in[2];
  float* out = (float*)d_out;
  char* ws = (char*)d_ws;

  u16* xb     = (u16*)(ws + 0);
  u16* wqkvT  = (u16*)(ws + 8388608);
  u16* woutT  = (u16*)(ws + 14680064);
  u16* qkv    = (u16*)(ws + 16777216);
  u16* qr     = (u16*)(ws + 41943040);
  u16* kr     = (u16*)(ws + 50331648);
  u16* vr     = (u16*)(ws + 58720256);
  u16* ao     = (u16*)(ws + 67108864);
  float* cosT = (float*)(ws + 75497472);
  float* sinT = (float*)(ws + 75759616);

  rope_table_kernel<<<256, 256, 0, stream>>>(cosT, sinT);
  cast_x_kernel<<<4096, 256, 0, stream>>>(x, xb);
  transpose_cast_kernel<<<dim3(96, 32), 256, 0, stream>>>(w_qkv, wqkvT, C_, F_);
  transpose_cast_kernel<<<dim3(32, 32), 256, 0, stream>>>(w_out, woutT, C_, C_);
  gemm_bt_kernel<u16><<<dim3(F_ / 128, M_ / 128), 256, 0, stream>>>(xb, wqkvT, qkv, M_, F_, C_);
  rope_reorg_kernel<<<8192, 256, 0, stream>>>(qkv, cosT, sinT, qr, kr, vr);
  attn_mfma_kernel<<<dim3(B_ * H_, T_ / 128), 256, 0, stream>>>(qr, kr, vr, ao);
  gemm_bt_kernel<float><<<dim3(C_ / 128, M_ / 128), 256, 0, stream>>>(ao, woutT, out, M_, C_, C_);
}

// Round 7
// 133.236 us; speedup vs baseline: 1.3580x; 1.3580x over previous
//
#include <hip/hip_runtime.h>
#include <stdint.h>

// ---------------------------------------------------------------------------
// MultiHeadSelfAttention: x(2,2048,1024) fp32, w_qkv(1024,3072), w_out(1024,1024)
// R6: (a) attn reverted to R4 structure (R5's 32q/wave spilled: WRITE_SIZE
// 8.2->17.4MB = scratch; 56-VGPR R4 version restored, keeping (__bf16) P-pack).
// (b) GEMMs: T3/T4 2-phase double-buffer — issue next tile's global_load_lds
// BEFORE compute, counted s_waitcnt vmcnt(4) + raw s_barrier (loads in flight
// across compute; m218-verified pattern).
// ---------------------------------------------------------------------------

#define B_ 2
#define T_ 2048
#define C_ 1024
#define H_ 16
#define D_ 64
#define F_ 3072
#define M_ 4096

typedef unsigned short u16;
typedef unsigned int u32;
typedef u16 u16x2 __attribute__((ext_vector_type(2)));
typedef u16 u16x4 __attribute__((ext_vector_type(4)));
typedef u16 u16x8 __attribute__((ext_vector_type(8)));
typedef __bf16 bf16x8 __attribute__((ext_vector_type(8)));
typedef float f32x4 __attribute__((ext_vector_type(4)));

__device__ __forceinline__ float b2f(u16 u) {
  union { unsigned int i; float f; } v; v.i = ((unsigned int)u) << 16; return v.f;
}
__device__ __forceinline__ u16 f2b(float f) {  // RNE, finite inputs
  unsigned int u = __float_as_uint(f);
  u += 0x7fffu + ((u >> 16) & 1u);
  return (u16)(u >> 16);
}
__device__ __forceinline__ bf16x8 u2b8(u16x8 v) {
  union { u16x8 u; bf16x8 b; } x; x.u = v; return x.b;
}

// --------------------------- small prep kernels ----------------------------

__global__ __launch_bounds__(256) void rope_table_kernel(float* cosT, float* sinT) {
  int idx = blockIdx.x * 256 + threadIdx.x;    // T_*32 = 65536 threads
  int t = idx >> 5, i = idx & 31;
  float inv_freq = powf(10000.0f, -(float)(2 * i) / 64.0f);
  float ang = (float)t * inv_freq;
  cosT[idx] = cosf(ang);
  sinT[idx] = sinf(ang);
}

__global__ __launch_bounds__(256) void cast_x_kernel(const float* __restrict__ x,
                                                     u16* __restrict__ xb) {
  int i = blockIdx.x * 256 + threadIdx.x;      // M_*C_/4 threads
  float4 v = ((const float4*)x)[i];
  u16x4 r;
  r[0] = f2b(v.x); r[1] = f2b(v.y); r[2] = f2b(v.z); r[3] = f2b(v.w);
  ((u16x4*)xb)[i] = r;
}

// out[c][r] = bf16(in[r][c]);  R rows, Ccol cols in input. 32x32 tiles.
__global__ __launch_bounds__(256) void transpose_cast_kernel(const float* __restrict__ in,
                                                             u16* __restrict__ out,
                                                             int R, int Ccol) {
  __shared__ float tile[32][33];
  int c0 = blockIdx.x * 32, r0 = blockIdx.y * 32;
  int tx = threadIdx.x & 31, ty = threadIdx.x >> 5;   // ty = 0..7
  #pragma unroll
  for (int i = 0; i < 32; i += 8)
    tile[ty + i][tx] = in[(size_t)(r0 + ty + i) * Ccol + c0 + tx];
  __syncthreads();
  #pragma unroll
  for (int i = 0; i < 32; i += 8)
    out[(size_t)(c0 + ty + i) * R + r0 + tx] = f2b(tile[tx][ty + i]);
}

// ------------------------------- MFMA GEMM ---------------------------------
// C[M,N] = A[M,K] * Bt[N,K]^T, bf16 in, TO out. 128x128 tile, BK=32, 4 waves,
// 4x4 16x16x32 frags. R6: 2-phase dbuf — STAGE(t+1) issued before compute(t),
// counted vmcnt(4) (4 loads/wave/tile stay in flight), raw s_barrier pair.
template <typename TO>
__global__ __launch_bounds__(256) void gemm_bt_kernel(const u16* __restrict__ A,
                                                      const u16* __restrict__ Bt,
                                                      TO* __restrict__ Cm,
                                                      int M, int N, int K) {
  __shared__ u16 sA[2][128 * 32];
  __shared__ u16 sB[2][128 * 32];
  const int tid = threadIdx.x;
  const int lane = tid & 63;
  const int wv = tid >> 6;
  const int wr = wv >> 1, wc = wv & 1;
  const int l16 = lane & 15, lq = lane >> 4;
  const int rowBase = blockIdx.y * 128;
  const int colBase = blockIdx.x * 128;

  f32x4 acc[4][4] = {};

  const int e0 = wv * 1024 + lane * 8;      // this lane's elem offset, chunk 0

  // 4 global_load_lds per wave per tile (2 A + 2 B), width 16B.
#define GSTAGE(buf, kk)                                                          \
  {                                                                              \
    _Pragma("unroll")                                                            \
    for (int s = 0; s < 2; ++s) {                                                \
      int e = e0 + s * 512;                                                      \
      int r = e >> 5, ccc = e & 31;                                              \
      __builtin_amdgcn_global_load_lds(                                          \
          (const __attribute__((address_space(1))) u32*)(A + (size_t)(rowBase + r) * K + (kk) + ccc), \
          (__attribute__((address_space(3))) u32*)&sA[buf][wv * 1024 + s * 512], 16, 0, 0); \
      __builtin_amdgcn_global_load_lds(                                          \
          (const __attribute__((address_space(1))) u32*)(Bt + (size_t)(colBase + r) * K + (kk) + ccc), \
          (__attribute__((address_space(3))) u32*)&sB[buf][wv * 1024 + s * 512], 16, 0, 0); \
    }                                                                            \
  }

  GSTAGE(0, 0);
  asm volatile("s_waitcnt vmcnt(0)" ::: "memory");
  __builtin_amdgcn_s_barrier();

  int cb = 0;
  for (int k0 = 0; k0 < K; k0 += 32, cb ^= 1) {
    const bool more = (k0 + 32 < K);
    if (more) {
      GSTAGE(cb ^ 1, k0 + 32);
      asm volatile("s_waitcnt vmcnt(4)" ::: "memory");  // current tile drained,
    } else {                                            // next 4 stay in flight
      asm volatile("s_waitcnt vmcnt(0)" ::: "memory");
    }
    __builtin_amdgcn_s_barrier();

    bf16x8 af[4], bf[4];
    #pragma unroll
    for (int m = 0; m < 4; ++m)
      af[m] = u2b8(*(const u16x8*)&sA[cb][(wr * 64 + m * 16 + l16) * 32 + lq * 8]);
    #pragma unroll
    for (int n = 0; n < 4; ++n)
      bf[n] = u2b8(*(const u16x8*)&sB[cb][(wc * 64 + n * 16 + l16) * 32 + lq * 8]);
    __builtin_amdgcn_s_setprio(1);
    #pragma unroll
    for (int m = 0; m < 4; ++m)
      #pragma unroll
      for (int n = 0; n < 4; ++n)
        acc[m][n] = __builtin_amdgcn_mfma_f32_16x16x32_bf16(af[m], bf[n], acc[m][n], 0, 0, 0);
    __builtin_amdgcn_s_setprio(0);
    __builtin_amdgcn_s_barrier();   // reads of buf[cb] done before t+1 overwrites it
  }
#undef GSTAGE

  // C/D layout (verified m89): col = lane&15, row = (lane>>4)*4 + reg
  #pragma unroll
  for (int m = 0; m < 4; ++m) {
    #pragma unroll
    for (int n = 0; n < 4; ++n) {
      int row = rowBase + wr * 64 + m * 16 + lq * 4;
      int col = colBase + wc * 64 + n * 16 + l16;
      #pragma unroll
      for (int j = 0; j < 4; ++j) {
        float v = acc[m][n][j];
        if constexpr (sizeof(TO) == 2) {
          Cm[(size_t)(row + j) * N + col] = f2b(v);
        } else {
          Cm[(size_t)(row + j) * N + col] = v;
        }
      }
    }
  }
}

// ----------------------------- RoPE + reorg --------------------------------
// qkv[M_,F_] bf16 -> qr/kr/vr [B,H,T,D] bf16 (rope on q,k; copy v)
// qr is PRE-SCALED by 0.125*log2(e) (exp2-domain softmax, single bf16 round).
__global__ __launch_bounds__(256) void rope_reorg_kernel(const u16* __restrict__ qkv,
                                                         const float* __restrict__ cosT,
                                                         const float* __restrict__ sinT,
                                                         u16* __restrict__ qr,
                                                         u16* __restrict__ kr,
                                                         u16* __restrict__ vr) {
  const float QSC = 0.125f * 1.44269504f;
  int idx = blockIdx.x * 256 + threadIdx.x;   // B*T*H*32 = 2^21 threads
  int d2 = idx & 31;
  int h = (idx >> 5) & 15;
  int t = (idx >> 9) & 2047;
  int b = idx >> 20;
  size_t base = (size_t)(b * T_ + t) * F_ + h * 64 + d2 * 2;
  float qe = b2f(qkv[base]),        qo = b2f(qkv[base + 1]);
  float ke = b2f(qkv[base + C_]),   ko = b2f(qkv[base + C_ + 1]);
  float cv = cosT[t * 32 + d2], sv = sinT[t * 32 + d2];
  size_t ob = ((size_t)(b * H_ + h) * T_ + t) * D_ + d2 * 2;
  qr[ob]     = f2b((qe * cv - qo * sv) * QSC);
  qr[ob + 1] = f2b((qe * sv + qo * cv) * QSC);
  kr[ob]     = f2b(ke * cv - ko * sv);
  kr[ob + 1] = f2b(ke * sv + ko * cv);
  vr[ob]     = qkv[base + 2 * C_];
  vr[ob + 1] = qkv[base + 2 * C_ + 1];
}

// ------------------------- MFMA flash attention ----------------------------
// R4 structure (proven 55.4us, 56 VGPR): 16 q-rows/wave, in-register P via
// k-slot permutation (V rows staged bit-permuted vrow=[b5 b2 b4 b3 b1 b0] so
// PV A-operand = own exp2'd registers). Swapped QK^T; softmax state in q=l16
// space, O accumulator in q=lq*4+j space; transfers via __shfl(.., lq*4+j).
// Only R5-keeper: P-pack via (__bf16) casts (v_cvt_pk_bf16_f32).
__global__ __launch_bounds__(256, 4) void attn_mfma_kernel(const u16* __restrict__ qr,
                                                           const u16* __restrict__ kr,
                                                           const u16* __restrict__ vr,
                                                           u16* __restrict__ ao) {
  constexpr int LDK = 72, LDVT = 72;
  __shared__ u16 sK[2][64 * LDK];
  __shared__ u16 sVt[2][64 * LDVT];              // sVt[buf][d][k-slot]

  const int tid = threadIdx.x;
  const int lane = tid & 63;
  const int w = tid >> 6;
  const int l16 = lane & 15, lq = lane >> 4;
  const int bh = blockIdx.x;
  const int qt = (int)gridDim.y - 1 - (int)blockIdx.y;   // long blocks first
  const int qbase = qt * 64;
  const size_t hb = (size_t)bh * (T_ * D_);

  // Q frags (pre-scaled bf16): rows qbase + w*16 + l16
  bf16x8 qv[2];
  #pragma unroll
  for (int dc = 0; dc < 2; ++dc) {
    int row = qbase + w * 16 + l16;
    qv[dc] = u2b8(*(const u16x8*)(qr + hb + (size_t)row * 64 + dc * 32 + lq * 8));
  }

  f32x4 o[4] = {};              // o[dt]: O[q=lq*4+j][d=dt*16+l16]
  float mrow = -1e30f;          // running max (log2 domain), row q=l16
  float lrow = 0.0f;            // per-lane partial denom, row q=l16

  // staging index maps
  const int skk = tid >> 3;           // K row 0..31 (and +32)
  const int sd0 = (tid & 7) * 8;      // K col octet
  const int vkp = tid & 31;           // V slot-pair 0..31 (slots 2vkp, 2vkp+1)
  const int vdb = tid >> 5;           // V d-block 0..7
  // true V row for slot r=2*vkp: vrow(r)=32*b5+16*b2+8*b4+4*b3+2*b1+b0 (r bits)
  const int vtr = ((vkp >> 4) & 1) * 32 + ((vkp >> 1) & 1) * 16 +
                  ((vkp >> 3) & 1) * 8 + ((vkp >> 2) & 1) * 4 + (vkp & 1) * 2;

  u16x8 rk0, rk1, rv0, rv1;
#define LOADKV(k0)                                                             \
  {                                                                            \
    rk0 = *(const u16x8*)(kr + hb + (size_t)((k0) + skk) * 64 + sd0);          \
    rk1 = *(const u16x8*)(kr + hb + (size_t)((k0) + 32 + skk) * 64 + sd0);     \
    rv0 = *(const u16x8*)(vr + hb + (size_t)((k0) + vtr) * 64 + vdb * 8);      \
    rv1 = *(const u16x8*)(vr + hb + (size_t)((k0) + vtr + 1) * 64 + vdb * 8);  \
  }
#define WRITEKV(buf)                                                           \
  {                                                                            \
    *(u16x8*)&sK[buf][skk * LDK + sd0] = rk0;                                  \
    *(u16x8*)&sK[buf][(32 + skk) * LDK + sd0] = rk1;                           \
    _Pragma("unroll")                                                          \
    for (int u = 0; u < 8; ++u) {                                              \
      u16x2 pk; pk[0] = rv0[u]; pk[1] = rv1[u];                                \
      *(u16x2*)&sVt[buf][(vdb * 8 + u) * LDVT + 2 * vkp] = pk;                 \
    }                                                                          \
  }

  LOADKV(0);
  WRITEKV(0);
  __syncthreads();

  const int nt = qt + 1;
  int cur = 0;
  for (int it = 0; it < nt; ++it) {
    const int k0 = it * 64;
    const bool more = (it + 1 < nt);
    if (more) LOADKV(k0 + 64);           // prefetch next tile into regs (T14)

    // ---- QK^T (swapped): accs[kt][j] = S[q=l16][slot k0+kt*16+lq*4+j]
    f32x4 accs[4] = {};
    __builtin_amdgcn_s_setprio(1);
    #pragma unroll
    for (int kt = 0; kt < 4; ++kt) {
      bf16x8 kf0 = u2b8(*(const u16x8*)&sK[cur][(kt * 16 + l16) * LDK + lq * 8]);
      bf16x8 kf1 = u2b8(*(const u16x8*)&sK[cur][(kt * 16 + l16) * LDK + 32 + lq * 8]);
      accs[kt] = __builtin_amdgcn_mfma_f32_16x16x32_bf16(kf0, qv[0], accs[kt], 0, 0, 0);
      accs[kt] = __builtin_amdgcn_mfma_f32_16x16x32_bf16(kf1, qv[1], accs[kt], 0, 0, 0);
    }
    __builtin_amdgcn_s_setprio(0);

    const int qrow = qbase + w * 16 + l16;
    if (k0 + 63 > qbase + w * 16) {      // wave-uniform: last tile only
      #pragma unroll
      for (int kt = 0; kt < 4; ++kt)
        #pragma unroll
        for (int j = 0; j < 4; ++j)
          if (k0 + kt * 16 + lq * 4 + j > qrow) accs[kt][j] = -1e30f;
    }
    // row max for q=l16: depth-4 tree + 2 shfl (k spread across lq groups)
    float m0 = fmaxf(fmaxf(accs[0][0], accs[0][1]), fmaxf(accs[0][2], accs[0][3]));
    float m1 = fmaxf(fmaxf(accs[1][0], accs[1][1]), fmaxf(accs[1][2], accs[1][3]));
    float m2 = fmaxf(fmaxf(accs[2][0], accs[2][1]), fmaxf(accs[2][2], accs[2][3]));
    float m3 = fmaxf(fmaxf(accs[3][0], accs[3][1]), fmaxf(accs[3][2], accs[3][3]));
    float mx = fmaxf(fmaxf(m0, m1), fmaxf(m2, m3));
    mx = fmaxf(mx, __shfl_xor(mx, 16));
    mx = fmaxf(mx, __shfl_xor(mx, 32));

    if (!__all(mx <= mrow)) {            // defer-max: exact skip when no new max
      float mnew = fmaxf(mrow, mx);
      float corr = __builtin_amdgcn_exp2f(mrow - mnew);   // row q=l16
      lrow *= corr;
      mrow = mnew;
      // broadcast corr into D-row space (q=lq*4+j) before scaling O
      f32x4 corrv;
      #pragma unroll
      for (int j = 0; j < 4; ++j) corrv[j] = __shfl(corr, lq * 4 + j);
      #pragma unroll
      for (int dt = 0; dt < 4; ++dt) o[dt] *= corrv;
    }
    const float mu = mrow;
    // exp2 + pack: pb[kc][u] : u<4 <- slot kt=2kc, u>=4 <- kt=2kc+1
    bf16x8 pb[2];
    float lsum = 0.0f;
    #pragma unroll
    for (int kt = 0; kt < 4; ++kt) {
      #pragma unroll
      for (int j = 0; j < 4; ++j) {
        float p = __builtin_amdgcn_exp2f(accs[kt][j] - mu);
        lsum += p;
        pb[kt >> 1][(kt & 1) * 4 + j] = (__bf16)p;   // -> v_cvt_pk_bf16_f32
      }
    }
    lrow += lsum;

    // ---- PV: A-operand = own registers (slot perm); B from sVt ----
    __builtin_amdgcn_s_setprio(1);
    #pragma unroll
    for (int kc = 0; kc < 2; ++kc) {
      #pragma unroll
      for (int dt = 0; dt < 4; ++dt) {
        bf16x8 vt = u2b8(*(const u16x8*)&sVt[cur][(dt * 16 + l16) * LDVT + kc * 32 + lq * 8]);
        o[dt] = __builtin_amdgcn_mfma_f32_16x16x32_bf16(pb[kc], vt, o[dt], 0, 0, 0);
      }
    }
    __builtin_amdgcn_s_setprio(0);

    if (more) WRITEKV(cur ^ 1);          // write prefetched tile to other buffer
    __syncthreads();                     // one barrier per tile
    cur ^= 1;
  }

  // finalize: full row denom in l16-space, broadcast 1/l into D-row space.
  const int b = bh >> 4, h = bh & 15;
  float l = lrow;
  l += __shfl_xor(l, 16);
  l += __shfl_xor(l, 32);
  float linv = 1.0f / l;
  #pragma unroll
  for (int j = 0; j < 4; ++j) {
    float lj = __shfl(linv, lq * 4 + j);   // lane r (r<16) holds row r's denom
    int row = qbase + w * 16 + lq * 4 + j;
    u16* orow = ao + ((size_t)(b * T_ + row)) * C_ + h * 64;
    #pragma unroll
    for (int dt = 0; dt < 4; ++dt)
      orow[dt * 16 + l16] = f2b(o[dt][j] * lj);
  }
}

// ------------------------------- launcher ----------------------------------
// ws layout (bytes):                              size
//   xb     @ 0           bf16 x           8,388,608
//   wqkvT  @ 8388608     bf16 w_qkv^T     6,291,456
//   woutT  @ 14680064    bf16 w_out^T     2,097,152
//   qkv    @ 16777216    bf16 qkv        25,165,824
//   qr     @ 41943040    bf16 [B,H,T,D]   8,388,608
//   kr     @ 50331648                     8,388,608
//   vr     @ 58720256                     8,388,608
//   ao     @ 67108864    bf16 attn out    8,388,608
//   cosT   @ 75497472    f32                262,144
//   sinT   @ 75759616    f32                262,144
extern "C" void kernel_launch(void* const* d_in, const int* in_sizes, int n_in,
                              void* d_out, int out_size, void* d_ws, size_t ws_size,
                              hipStream_t stream) {
  const float* x     = (const float*)d_in[0];
  const float* w_qkv = (const float*)d_in[1];
  const float* w_out = (const float*)d_in[2];
  float* out = (float*)d_out;
  char* ws = (char*)d_ws;

  u16* xb     = (u16*)(ws + 0);
  u16* wqkvT  = (u16*)(ws + 8388608);
  u16* woutT  = (u16*)(ws + 14680064);
  u16* qkv    = (u16*)(ws + 16777216);
  u16* qr     = (u16*)(ws + 41943040);
  u16* kr     = (u16*)(ws + 50331648);
  u16* vr     = (u16*)(ws + 58720256);
  u16* ao     = (u16*)(ws + 67108864);
  float* cosT = (float*)(ws + 75497472);
  float* sinT = (float*)(ws + 75759616);

  rope_table_kernel<<<256, 256, 0, stream>>>(cosT, sinT);
  cast_x_kernel<<<4096, 256, 0, stream>>>(x, xb);
  transpose_cast_kernel<<<dim3(96, 32), 256, 0, stream>>>(w_qkv, wqkvT, C_, F_);
  transpose_cast_kernel<<<dim3(32, 32), 256, 0, stream>>>(w_out, woutT, C_, C_);
  gemm_bt_kernel<u16><<<dim3(F_ / 128, M_ / 128), 256, 0, stream>>>(xb, wqkvT, qkv, M_, F_, C_);
  rope_reorg_kernel<<<8192, 256, 0, stream>>>(qkv, cosT, sinT, qr, kr, vr);
  attn_mfma_kernel<<<dim3(B_ * H_, T_ / 64), 256, 0, stream>>>(qr, kr, vr, ao);
  gemm_bt_kernel<float><<<dim3(C_ / 128, M_ / 128), 256, 0, stream>>>(ao, woutT, out, M_, C_, C_);
}